// Round 13
// baseline (332.901 us; speedup 1.0000x reference)
//
#include <hip/hip_runtime.h>
#include <hip/hip_bf16.h>

#define BB 8
#define SS 2048
#define DD 384
#define HH 8
#define HD 48
#define QT 32
#define KT 64

typedef unsigned short u16;
typedef unsigned int u32;
typedef unsigned short u16x4 __attribute__((ext_vector_type(4)));
typedef unsigned short u16x8 __attribute__((ext_vector_type(8)));
typedef unsigned int u32x2 __attribute__((ext_vector_type(2)));
typedef short s16x8 __attribute__((ext_vector_type(8)));
typedef float f32x4 __attribute__((ext_vector_type(4)));

__device__ __forceinline__ float bf2f(u16 v){
  union { u32 u; float f; } x; x.u = ((u32)v) << 16; return x.f;
}
__device__ __forceinline__ u16 f2bf(float f){
  union { float f; u32 u; } x; x.f = f;
  u32 r = x.u + 0x7fffu + ((x.u >> 16) & 1u);
  return (u16)(r >> 16);
}
// split fp32 into hi (truncated bf16) + lo (bf16 of residual); hi+lo ~ 17-bit mantissa
__device__ __forceinline__ void split2(float f, u16& h, u16& l){
  union { float f; u32 u; } x; x.f = f;
  h = (u16)(x.u >> 16);
  l = f2bf(f - bf2f(h));
}
// pack two f32 -> two truncated bf16 in one u32 (lo = a, hi = b)
__device__ __forceinline__ u32 pack_trunc2(float a, float b){
  union { float f; u32 u; } xa, xb; xa.f = a; xb.f = b;
  return (xa.u >> 16) | (xb.u & 0xffff0000u);
}

// lgkm-only barrier: LDS writes visible, but global loads stay in flight
#define LBAR() do { \
  asm volatile("s_waitcnt lgkmcnt(0)" ::: "memory"); \
  __builtin_amdgcn_s_barrier(); \
  asm volatile("" ::: "memory"); \
} while (0)

// ---------------- Kernel 1: QKV projection, split-bf16 MFMA GEMM ----------------
// (round-6 proven version) C = x * Wqkv^T ; scatter to Q (pre-scaled by
// log2(e)/sqrt(48)), K ([B,H,S,48]) and V^T ([B,H,48,S]) bf16 with bias.
__global__ __launch_bounds__(512, 4) void qkv_gemm(
    const float* __restrict__ x, const float* __restrict__ W,
    const float* __restrict__ bias,
    u16* __restrict__ Q, u16* __restrict__ Kd, u16* __restrict__ Vt)
{
  __shared__ u16 Ah[128][40], Al[128][40], Bh[128][40], Bl[128][40];
  const int tid  = threadIdx.x;
  const int w    = tid >> 6, lane = tid & 63;
  const int lg   = lane >> 4, ln = lane & 15;
  const int wm   = w >> 1, wn = w & 1;
  const int mb   = blockIdx.x / 9, nb = blockIdx.x % 9;
  const int m0   = mb * 128, n0 = nb * 128;
  const int srow = tid >> 3, sk4 = (tid & 7) << 2;
  const float qscale = 0.2082350972f;  // log2(e)/sqrt(48)

  f32x4 acc[8];
  #pragma unroll
  for (int i = 0; i < 8; i++) acc[i] = (f32x4){0.f,0.f,0.f,0.f};

  for (int ks = 0; ks < 12; ks++){
    const int k0 = ks * 32;
    __syncthreads();
    #pragma unroll
    for (int p = 0; p < 2; p++){
      const int row = srow + p*64;
      float4 av = *(const float4*)(x + (long)(m0+row)*DD + k0 + sk4);
      float4 bv = *(const float4*)(W + (long)(n0+row)*DD + k0 + sk4);
      u16 h0,l0,h1,l1,h2,l2,h3,l3;
      split2(av.x,h0,l0); split2(av.y,h1,l1); split2(av.z,h2,l2); split2(av.w,h3,l3);
      *(u16x4*)&Ah[row][sk4] = (u16x4){h0,h1,h2,h3};
      *(u16x4*)&Al[row][sk4] = (u16x4){l0,l1,l2,l3};
      split2(bv.x,h0,l0); split2(bv.y,h1,l1); split2(bv.z,h2,l2); split2(bv.w,h3,l3);
      *(u16x4*)&Bh[row][sk4] = (u16x4){h0,h1,h2,h3};
      *(u16x4*)&Bl[row][sk4] = (u16x4){l0,l1,l2,l3};
    }
    __syncthreads();
    s16x8 bh[4], bl[4];
    #pragma unroll
    for (int fn = 0; fn < 4; fn++){
      const int br = wn*64 + fn*16 + ln;
      bh[fn] = *(const s16x8*)&Bh[br][lg*8];
      bl[fn] = *(const s16x8*)&Bl[br][lg*8];
    }
    #pragma unroll
    for (int fm = 0; fm < 2; fm++){
      const int ar = wm*32 + fm*16 + ln;
      s16x8 ah = *(const s16x8*)&Ah[ar][lg*8];
      s16x8 al = *(const s16x8*)&Al[ar][lg*8];
      #pragma unroll
      for (int fn = 0; fn < 4; fn++){
        f32x4 c = acc[fm*4+fn];
        c = __builtin_amdgcn_mfma_f32_16x16x32_bf16(ah, bh[fn], c, 0, 0, 0);
        c = __builtin_amdgcn_mfma_f32_16x16x32_bf16(ah, bl[fn], c, 0, 0, 0);
        c = __builtin_amdgcn_mfma_f32_16x16x32_bf16(al, bh[fn], c, 0, 0, 0);
        acc[fm*4+fn] = c;
      }
    }
  }
  #pragma unroll
  for (int fm = 0; fm < 2; fm++){
    #pragma unroll
    for (int fn = 0; fn < 4; fn++){
      const int e = n0 + wn*64 + fn*16 + ln;
      const float bi = bias[e];
      const int h = e / 144, c = e % 144;
      #pragma unroll
      for (int r = 0; r < 4; r++){
        const int mm = m0 + wm*32 + fm*16 + lg*4 + r;
        const int bb = mm >> 11, s = mm & 2047;
        const float v = acc[fm*4+fn][r] + bi;
        if (c < 48)       Q[(((long)(bb*HH + h))*SS + s)*HD + c] = f2bf(v * qscale);
        else if (c < 96)  Kd[(((long)(bb*HH + h))*SS + s)*HD + (c-48)] = f2bf(v);
        else              Vt[(((long)(bb*HH + h))*HD + (c-96))*SS + s] = f2bf(v);
      }
    }
  }
}

// ---------------- Kernel 2: MFMA attention, KT=64 + partial K double-buffer ----------------
// r11 structure (64 keys / 2 barriers per iter, b64-packed softmax) with its
// one diagnosed flaw fixed: K subtiles 0-1 are register-prefetched one iter
// ahead (persistent dbuf, +32 VGPR); subtiles 2-3 issue at iter top and their
// latency hides under the QK^T MFMAs of the prefetched half.
__global__ __launch_bounds__(512, 4) void attn_kernel(
    const u16* __restrict__ Q, const u16* __restrict__ K,
    const u16* __restrict__ Vg, float* __restrict__ vals)
{
  __shared__ u16 Ss[HH][QT][72];   // bf16 scores [h][q][64k+pad], 144B rows
  __shared__ u16 Pb[HH][QT][72];   // bf16 P [h][q][64k+pad]

  const int tid  = threadIdx.x;
  const int h    = tid >> 6;
  const int lane = tid & 63;
  // XCD-chunked swizzle: 512 blocks, 8 XCDs -> XCD x gets exactly batch b=x.
  const int wg   = ((int)blockIdx.x % 8) * 64 + (int)blockIdx.x / 8;
  const int b    = wg >> 6;
  const int qt   = wg & 63;
  const int q0   = qt * QT;
  const int lg   = lane >> 4;
  const int ln   = lane & 15;

  const long hbase = ((long)(b*HH + h)) * SS;
  const u16* vbase = Vg + ((long)(b*HH + h)) * HD * SS;
  const s16x8 z8 = (s16x8){0,0,0,0,0,0,0,0};

  // Q fragments (B operand of swapped QK^T) for both subtiles, held all kernel.
  s16x8 qf0[2], qf1[2];
  #pragma unroll
  for (int qs = 0; qs < 2; qs++){
    const u16* qp = Q + (hbase + q0 + qs*16 + ln)*HD;
    qf0[qs] = *(const s16x8*)(qp + lg*8);
    if (lane < 32) qf1[qs] = *(const s16x8*)(qp + 32 + lg*8);
    else           qf1[qs] = z8;
  }

  f32x4 oacc[2][3];
  #pragma unroll
  for (int qs = 0; qs < 2; qs++)
    #pragma unroll
    for (int c = 0; c < 3; c++) oacc[qs][c] = (f32x4){0.f,0.f,0.f,0.f};

  // softmax mapping: thread owns (q = tid>>4, k = smk4 .. smk4+3)
  const int smq = tid >> 4, smk4 = (tid & 15) << 2;

  // persistent K double-buffer for subtiles 0-1 (first 32 keys of each tile)
  s16x8 kfA[2][2], kfB[2][2];
  #pragma unroll
  for (int nt = 0; nt < 2; nt++){
    const u16* kp = K + (hbase + nt*16 + ln)*HD;
    kfA[0][nt] = *(const s16x8*)(kp + lg*8);
    if (lane < 32) kfB[0][nt] = *(const s16x8*)(kp + 32 + lg*8);
    else           kfB[0][nt] = z8;
  }

  int k0 = 0;
#define STEP(CUR, NXT) { \
    /* V fragments: issued now, consumed after both barriers */ \
    s16x8 vf[3][2]; \
    _Pragma("unroll") \
    for (int c = 0; c < 3; c++) \
      _Pragma("unroll") \
      for (int ks2 = 0; ks2 < 2; ks2++) \
        vf[c][ks2] = *(const s16x8*)(vbase + (long)(c*16 + ln)*SS + k0 + ks2*32 + lg*8); \
    /* transient K loads for subtiles 2-3 of THIS tile (hidden under QK^T 0-1) */ \
    s16x8 ktA[2], ktB[2]; \
    _Pragma("unroll") \
    for (int nt = 0; nt < 2; nt++){ \
      const u16* kp = K + (hbase + k0 + (nt+2)*16 + ln)*HD; \
      ktA[nt] = *(const s16x8*)(kp + lg*8); \
      if (lane < 32) ktB[nt] = *(const s16x8*)(kp + 32 + lg*8); \
      else           ktB[nt] = z8; \
    } \
    /* prefetch subtiles 0-1 of NEXT tile into buf NXT */ \
    const int knx = (k0 + KT) & (SS - 1); \
    _Pragma("unroll") \
    for (int nt = 0; nt < 2; nt++){ \
      const u16* kp = K + (hbase + knx + nt*16 + ln)*HD; \
      kfA[NXT][nt] = *(const s16x8*)(kp + lg*8); \
      if (lane < 32) kfB[NXT][nt] = *(const s16x8*)(kp + 32 + lg*8); \
      else           kfB[NXT][nt] = z8; \
    } \
    /* QK^T (swapped): D[k][q]; subtiles 0-1 from regs, 2-3 from transient */ \
    __builtin_amdgcn_s_setprio(1); \
    _Pragma("unroll") \
    for (int nt = 0; nt < 2; nt++){ \
      _Pragma("unroll") \
      for (int qs = 0; qs < 2; qs++){ \
        f32x4 a = (f32x4){0.f,0.f,0.f,0.f}; \
        a = __builtin_amdgcn_mfma_f32_16x16x32_bf16(kfA[CUR][nt], qf0[qs], a, 0, 0, 0); \
        a = __builtin_amdgcn_mfma_f32_16x16x32_bf16(kfB[CUR][nt], qf1[qs], a, 0, 0, 0); \
        u32x2 pw; pw[0] = pack_trunc2(a[0], a[1]); pw[1] = pack_trunc2(a[2], a[3]); \
        *(u32x2*)&Ss[h][qs*16 + ln][nt*16 + lg*4] = pw; \
      } \
    } \
    _Pragma("unroll") \
    for (int nt = 0; nt < 2; nt++){ \
      _Pragma("unroll") \
      for (int qs = 0; qs < 2; qs++){ \
        f32x4 a = (f32x4){0.f,0.f,0.f,0.f}; \
        a = __builtin_amdgcn_mfma_f32_16x16x32_bf16(ktA[nt], qf0[qs], a, 0, 0, 0); \
        a = __builtin_amdgcn_mfma_f32_16x16x32_bf16(ktB[nt], qf1[qs], a, 0, 0, 0); \
        u32x2 pw; pw[0] = pack_trunc2(a[0], a[1]); pw[1] = pack_trunc2(a[2], a[3]); \
        *(u32x2*)&Ss[h][qs*16 + ln][(nt+2)*16 + lg*4] = pw; \
      } \
    } \
    __builtin_amdgcn_s_setprio(0); \
    LBAR();   /* Ss visible; orders prev PV Pb-reads vs softmax writes */ \
    /* softmax over 8 heads; thread owns (smq, smk4..+3), b64 packed I/O */ \
    { \
      float e0[8], e1[8], e2[8], e3[8]; \
      float s0 = 0.f, s1 = 0.f, s2 = 0.f, s3 = 0.f; \
      _Pragma("unroll") \
      for (int hh = 0; hh < 8; hh++){ \
        u32x2 wv = *(const u32x2*)&Ss[hh][smq][smk4]; \
        union { u32 u; float f; } a0, a1, a2, a3; \
        a0.u = wv[0] << 16; a1.u = wv[0] & 0xffff0000u; \
        a2.u = wv[1] << 16; a3.u = wv[1] & 0xffff0000u; \
        e0[hh] = __builtin_amdgcn_exp2f(a0.f); \
        e1[hh] = __builtin_amdgcn_exp2f(a1.f); \
        e2[hh] = __builtin_amdgcn_exp2f(a2.f); \
        e3[hh] = __builtin_amdgcn_exp2f(a3.f); \
        s0 += e0[hh]; s1 += e1[hh]; s2 += e2[hh]; s3 += e3[hh]; \
      } \
      float r0 = __builtin_amdgcn_rcpf(s0); \
      float r1 = __builtin_amdgcn_rcpf(s1); \
      float r2 = __builtin_amdgcn_rcpf(s2); \
      float r3 = __builtin_amdgcn_rcpf(s3); \
      _Pragma("unroll") \
      for (int hh = 0; hh < 8; hh++){ \
        u32x2 pw; \
        pw[0] = pack_trunc2(e0[hh]*r0, e1[hh]*r1); \
        pw[1] = pack_trunc2(e2[hh]*r2, e3[hh]*r3); \
        *(u32x2*)&Pb[hh][smq][smk4] = pw; \
      } \
    } \
    LBAR();   /* Pb visible; orders softmax Ss-reads vs next-iter writes */ \
    /* PV: O[32q][48d] += P[32q][64k] * V[64k][48d] */ \
    __builtin_amdgcn_s_setprio(1); \
    _Pragma("unroll") \
    for (int qs = 0; qs < 2; qs++){ \
      _Pragma("unroll") \
      for (int ks2 = 0; ks2 < 2; ks2++){ \
        s16x8 pf = *(const s16x8*)&Pb[h][qs*16 + ln][ks2*32 + lg*8]; \
        oacc[qs][0] = __builtin_amdgcn_mfma_f32_16x16x32_bf16(pf, vf[0][ks2], oacc[qs][0], 0, 0, 0); \
        oacc[qs][1] = __builtin_amdgcn_mfma_f32_16x16x32_bf16(pf, vf[1][ks2], oacc[qs][1], 0, 0, 0); \
        oacc[qs][2] = __builtin_amdgcn_mfma_f32_16x16x32_bf16(pf, vf[2][ks2], oacc[qs][2], 0, 0, 0); \
      } \
    } \
    __builtin_amdgcn_s_setprio(0); \
    k0 = knx; \
  }

  for (int t2 = 0; t2 < SS/KT/2; t2++){
    STEP(0, 1)
    STEP(1, 0)
  }
#undef STEP

  // store vals[b][h][q][d] fp32 (bug-compatible flat layout)
  float* op = vals + (hbase + q0)*HD;
  #pragma unroll
  for (int qs = 0; qs < 2; qs++)
    #pragma unroll
    for (int c = 0; c < 3; c++)
      #pragma unroll
      for (int r = 0; r < 4; r++)
        op[(long)(qs*16 + lg*4 + r)*HD + c*16 + ln] = oacc[qs][c][r];
}

// ---------------- Kernel 3: output projection, split-bf16 MFMA GEMM ----------------
// (round-6 proven version)
__global__ __launch_bounds__(512, 4) void out_gemm(
    const float* __restrict__ A, const float* __restrict__ W,
    const float* __restrict__ bias, float* __restrict__ out)
{
  __shared__ u16 Ah[128][40], Al[128][40], Bh[128][40], Bl[128][40];
  const int tid  = threadIdx.x;
  const int w    = tid >> 6, lane = tid & 63;
  const int lg   = lane >> 4, ln = lane & 15;
  const int wm   = w >> 1, wn = w & 1;
  const int mb   = blockIdx.x / 3, nb = blockIdx.x % 3;
  const int m0   = mb * 128, n0 = nb * 128;
  const int srow = tid >> 3, sk4 = (tid & 7) << 2;

  f32x4 acc[8];
  #pragma unroll
  for (int i = 0; i < 8; i++) acc[i] = (f32x4){0.f,0.f,0.f,0.f};

  for (int ks = 0; ks < 12; ks++){
    const int k0 = ks * 32;
    __syncthreads();
    #pragma unroll
    for (int p = 0; p < 2; p++){
      const int row = srow + p*64;
      float4 av = *(const float4*)(A + (long)(m0+row)*DD + k0 + sk4);
      float4 bv = *(const float4*)(W + (long)(n0+row)*DD + k0 + sk4);
      u16 h0,l0,h1,l1,h2,l2,h3,l3;
      split2(av.x,h0,l0); split2(av.y,h1,l1); split2(av.z,h2,l2); split2(av.w,h3,l3);
      *(u16x4*)&Ah[row][sk4] = (u16x4){h0,h1,h2,h3};
      *(u16x4*)&Al[row][sk4] = (u16x4){l0,l1,l2,l3};
      split2(bv.x,h0,l0); split2(bv.y,h1,l1); split2(bv.z,h2,l2); split2(bv.w,h3,l3);
      *(u16x4*)&Bh[row][sk4] = (u16x4){h0,h1,h2,h3};
      *(u16x4*)&Bl[row][sk4] = (u16x4){l0,l1,l2,l3};
    }
    __syncthreads();
    s16x8 bh[4], bl[4];
    #pragma unroll
    for (int fn = 0; fn < 4; fn++){
      const int br = wn*64 + fn*16 + ln;
      bh[fn] = *(const s16x8*)&Bh[br][lg*8];
      bl[fn] = *(const s16x8*)&Bl[br][lg*8];
    }
    #pragma unroll
    for (int fm = 0; fm < 2; fm++){
      const int ar = wm*32 + fm*16 + ln;
      s16x8 ah = *(const s16x8*)&Ah[ar][lg*8];
      s16x8 al = *(const s16x8*)&Al[ar][lg*8];
      #pragma unroll
      for (int fn = 0; fn < 4; fn++){
        f32x4 c = acc[fm*4+fn];
        c = __builtin_amdgcn_mfma_f32_16x16x32_bf16(ah, bh[fn], c, 0, 0, 0);
        c = __builtin_amdgcn_mfma_f32_16x16x32_bf16(ah, bl[fn], c, 0, 0, 0);
        c = __builtin_amdgcn_mfma_f32_16x16x32_bf16(al, bh[fn], c, 0, 0, 0);
        acc[fm*4+fn] = c;
      }
    }
  }
  #pragma unroll
  for (int fm = 0; fm < 2; fm++){
    #pragma unroll
    for (int fn = 0; fn < 4; fn++){
      const int e = n0 + wn*64 + fn*16 + ln;
      const float bi = bias[e];
      #pragma unroll
      for (int r = 0; r < 4; r++){
        const int mm = m0 + wm*32 + fm*16 + lg*4 + r;
        out[(long)mm*DD + e] = acc[fm*4+fn][r] + bi;
      }
    }
  }
}

extern "C" void kernel_launch(void* const* d_in, const int* in_sizes, int n_in,
                              void* d_out, int out_size, void* d_ws, size_t ws_size,
                              hipStream_t stream)
{
  const float* x    = (const float*)d_in[0];
  const float* Wqkv = (const float*)d_in[1];
  const float* bqkv = (const float*)d_in[2];
  const float* Wo   = (const float*)d_in[3];
  const float* bo   = (const float*)d_in[4];
  float* out = (float*)d_out;

  const size_t QSZ = (size_t)BB*HH*SS*HD;   // 6,291,456 elems
  u16* Q  = (u16*)d_ws;
  u16* K  = Q + QSZ;
  u16* Vt = K + QSZ;                        // V^T [B,H,48,S]
  float* vals = (float*)(Vt + QSZ);         // fp32, 25.2 MB

  qkv_gemm<<<1152, 512, 0, stream>>>(x, Wqkv, bqkv, Q, K, Vt);
  attn_kernel<<<512, 512, 0, stream>>>(Q, K, Vt, vals);
  out_gemm<<<384, 512, 0, stream>>>(vals, Wo, bo, out);
}

// Round 14
// 222.965 us; speedup vs baseline: 1.4931x; 1.4931x over previous
//
#include <hip/hip_runtime.h>
#include <hip/hip_bf16.h>

#define BB 8
#define SS 2048
#define DD 384
#define HH 8
#define HD 48
#define QT 32
#define KT 32

typedef unsigned short u16;
typedef unsigned short u16x4 __attribute__((ext_vector_type(4)));
typedef unsigned short u16x8 __attribute__((ext_vector_type(8)));
typedef short s16x8 __attribute__((ext_vector_type(8)));
typedef float f32x4 __attribute__((ext_vector_type(4)));

__device__ __forceinline__ float bf2f(u16 v){
  union { unsigned int u; float f; } x; x.u = ((unsigned int)v) << 16; return x.f;
}
__device__ __forceinline__ u16 f2bf(float f){
  union { float f; unsigned int u; } x; x.f = f;
  unsigned int r = x.u + 0x7fffu + ((x.u >> 16) & 1u);
  return (u16)(r >> 16);
}
// truncating bf16 (1 VALU op); used only for P in [0,1] where bias ~2^-9 is invisible
__device__ __forceinline__ u16 f2bf_trunc(float f){
  union { float f; unsigned int u; } x; x.f = f;
  return (u16)(x.u >> 16);
}
// split fp32 into hi (truncated bf16) + lo (bf16 of residual); hi+lo ~ 17-bit mantissa
__device__ __forceinline__ void split2(float f, u16& h, u16& l){
  union { float f; unsigned int u; } x; x.f = f;
  h = (u16)(x.u >> 16);
  l = f2bf(f - bf2f(h));
}

// lgkm-only barrier: LDS writes visible, but global loads stay in flight
#define LBAR() do { \
  asm volatile("s_waitcnt lgkmcnt(0)" ::: "memory"); \
  __builtin_amdgcn_s_barrier(); \
  asm volatile("" ::: "memory"); \
} while (0)

// ---------------- Kernel 1: QKV projection, split-bf16 MFMA GEMM ----------------
// C[16384 x 1152] = x[16384 x 384] * Wqkv^T ; scatter to Q (pre-scaled by
// log2(e)/sqrt(48) so attn softmax can use exp2), K ([B,H,S,48]) and
// V^T ([B,H,48,S]) bf16 with bias.
__global__ __launch_bounds__(512, 4) void qkv_gemm(
    const float* __restrict__ x, const float* __restrict__ W,
    const float* __restrict__ bias,
    u16* __restrict__ Q, u16* __restrict__ Kd, u16* __restrict__ Vt)
{
  __shared__ u16 Ah[128][40], Al[128][40], Bh[128][40], Bl[128][40];
  const int tid  = threadIdx.x;
  const int w    = tid >> 6, lane = tid & 63;
  const int lg   = lane >> 4, ln = lane & 15;
  const int wm   = w >> 1, wn = w & 1;
  const int mb   = blockIdx.x / 9, nb = blockIdx.x % 9;
  const int m0   = mb * 128, n0 = nb * 128;
  const int srow = tid >> 3, sk4 = (tid & 7) << 2;
  const float qscale = 0.2082350972f;  // log2(e)/sqrt(48)

  f32x4 acc[8];
  #pragma unroll
  for (int i = 0; i < 8; i++) acc[i] = (f32x4){0.f,0.f,0.f,0.f};

  for (int ks = 0; ks < 12; ks++){
    const int k0 = ks * 32;
    __syncthreads();
    #pragma unroll
    for (int p = 0; p < 2; p++){
      const int row = srow + p*64;
      float4 av = *(const float4*)(x + (long)(m0+row)*DD + k0 + sk4);
      float4 bv = *(const float4*)(W + (long)(n0+row)*DD + k0 + sk4);
      u16 h0,l0,h1,l1,h2,l2,h3,l3;
      split2(av.x,h0,l0); split2(av.y,h1,l1); split2(av.z,h2,l2); split2(av.w,h3,l3);
      *(u16x4*)&Ah[row][sk4] = (u16x4){h0,h1,h2,h3};
      *(u16x4*)&Al[row][sk4] = (u16x4){l0,l1,l2,l3};
      split2(bv.x,h0,l0); split2(bv.y,h1,l1); split2(bv.z,h2,l2); split2(bv.w,h3,l3);
      *(u16x4*)&Bh[row][sk4] = (u16x4){h0,h1,h2,h3};
      *(u16x4*)&Bl[row][sk4] = (u16x4){l0,l1,l2,l3};
    }
    __syncthreads();
    s16x8 bh[4], bl[4];
    #pragma unroll
    for (int fn = 0; fn < 4; fn++){
      const int br = wn*64 + fn*16 + ln;
      bh[fn] = *(const s16x8*)&Bh[br][lg*8];
      bl[fn] = *(const s16x8*)&Bl[br][lg*8];
    }
    #pragma unroll
    for (int fm = 0; fm < 2; fm++){
      const int ar = wm*32 + fm*16 + ln;
      s16x8 ah = *(const s16x8*)&Ah[ar][lg*8];
      s16x8 al = *(const s16x8*)&Al[ar][lg*8];
      #pragma unroll
      for (int fn = 0; fn < 4; fn++){
        f32x4 c = acc[fm*4+fn];
        c = __builtin_amdgcn_mfma_f32_16x16x32_bf16(ah, bh[fn], c, 0, 0, 0);
        c = __builtin_amdgcn_mfma_f32_16x16x32_bf16(ah, bl[fn], c, 0, 0, 0);
        c = __builtin_amdgcn_mfma_f32_16x16x32_bf16(al, bh[fn], c, 0, 0, 0);
        acc[fm*4+fn] = c;
      }
    }
  }
  // epilogue: row = lg*4+r (M=token), col = ln (N=e); scatter
  #pragma unroll
  for (int fm = 0; fm < 2; fm++){
    #pragma unroll
    for (int fn = 0; fn < 4; fn++){
      const int e = n0 + wn*64 + fn*16 + ln;
      const float bi = bias[e];
      const int h = e / 144, c = e % 144;
      #pragma unroll
      for (int r = 0; r < 4; r++){
        const int mm = m0 + wm*32 + fm*16 + lg*4 + r;
        const int bb = mm >> 11, s = mm & 2047;
        const float v = acc[fm*4+fn][r] + bi;
        if (c < 48){
          Q[(((long)(bb*HH + h))*SS + s)*HD + c] = f2bf(v * qscale);
        } else if (c < 96){
          Kd[(((long)(bb*HH + h))*SS + s)*HD + (c-48)] = f2bf(v);
        } else {
          // V transposed: [B,H,48,S]
          Vt[(((long)(bb*HH + h))*HD + (c-96))*SS + s] = f2bf(v);
        }
      }
    }
  }
}

// ---------------- Kernel 2: MFMA attention with head-softmax ----------------
// Block: one (b, 32-query tile), 8 waves = 8 heads, 2 q-subtiles per wave.
// K fragments double-buffered across k-tiles (prefetched one iter ahead);
// V fragments issued at iter top, consumed at iter end. Two lgkm-only
// barriers per iteration keep all global loads in flight across barriers.
// Softmax uses exp2 (log2e folded into Q) + hardware rcp.
__global__ __launch_bounds__(512, 4) void attn_kernel(
    const u16* __restrict__ Q, const u16* __restrict__ K,
    const u16* __restrict__ Vg, float* __restrict__ vals)
{
  __shared__ float Ss[HH][QT][36];   // scores f32 [h][q][k]
  __shared__ u16  Pb[HH][QT][40];    // P bf16 [h][q][k] (MFMA A layout)

  const int tid  = threadIdx.x;
  const int h    = tid >> 6;
  const int lane = tid & 63;
  // XCD-chunked swizzle: 512 blocks, 8 XCDs -> XCD x gets exactly batch b=x.
  const int wg   = ((int)blockIdx.x % 8) * 64 + (int)blockIdx.x / 8;
  const int b    = wg >> 6;
  const int qt   = wg & 63;
  const int q0   = qt * QT;
  const int lg   = lane >> 4;
  const int ln   = lane & 15;

  const long hbase = ((long)(b*HH + h)) * SS;
  const u16* vbase = Vg + ((long)(b*HH + h)) * HD * SS;
  const s16x8 z8 = (s16x8){0,0,0,0,0,0,0,0};

  // Q fragments (B operand of swapped QK^T) for both subtiles, held all kernel.
  s16x8 qf0[2], qf1[2];
  #pragma unroll
  for (int qs = 0; qs < 2; qs++){
    const u16* qp = Q + (hbase + q0 + qs*16 + ln)*HD;
    qf0[qs] = *(const s16x8*)(qp + lg*8);
    if (lane < 32) qf1[qs] = *(const s16x8*)(qp + 32 + lg*8);
    else           qf1[qs] = z8;
  }

  f32x4 oacc[2][3];
  #pragma unroll
  for (int qs = 0; qs < 2; qs++)
    #pragma unroll
    for (int c = 0; c < 3; c++) oacc[qs][c] = (f32x4){0.f,0.f,0.f,0.f};

  const int sq0 = tid >> 5, sk = tid & 31;

  // K fragment double buffer: [buf][nt]; A = d0..31 slice, B = d32..47+pad
  s16x8 kfA[2][2], kfB[2][2];
  int k0 = 0;
  #pragma unroll
  for (int nt = 0; nt < 2; nt++){
    const u16* kp = K + (hbase + nt*16 + ln)*HD;
    kfA[0][nt] = *(const s16x8*)(kp + lg*8);
    if (lane < 32) kfB[0][nt] = *(const s16x8*)(kp + 32 + lg*8);
    else           kfB[0][nt] = z8;
  }

#define STEP(CUR, NXT) { \
    /* V(t) fragments: issued now, consumed after both barriers */ \
    s16x8 vf0 = *(const s16x8*)(vbase + (long)(     ln)*SS + k0 + lg*8); \
    s16x8 vf1 = *(const s16x8*)(vbase + (long)(16 + ln)*SS + k0 + lg*8); \
    s16x8 vf2 = *(const s16x8*)(vbase + (long)(32 + ln)*SS + k0 + lg*8); \
    /* K(t+1) prefetch into buf NXT */ \
    const int knx = (k0 + KT) & (SS - 1); \
    _Pragma("unroll") \
    for (int nt = 0; nt < 2; nt++){ \
      const u16* kp = K + (hbase + knx + nt*16 + ln)*HD; \
      kfA[NXT][nt] = *(const s16x8*)(kp + lg*8); \
      if (lane < 32) kfB[NXT][nt] = *(const s16x8*)(kp + 32 + lg*8); \
      else           kfB[NXT][nt] = z8; \
    } \
    /* QK^T (swapped): D[k][q] from buf CUR */ \
    __builtin_amdgcn_s_setprio(1); \
    _Pragma("unroll") \
    for (int nt = 0; nt < 2; nt++){ \
      _Pragma("unroll") \
      for (int qs = 0; qs < 2; qs++){ \
        f32x4 a = (f32x4){0.f,0.f,0.f,0.f}; \
        a = __builtin_amdgcn_mfma_f32_16x16x32_bf16(kfA[CUR][nt], qf0[qs], a, 0, 0, 0); \
        a = __builtin_amdgcn_mfma_f32_16x16x32_bf16(kfB[CUR][nt], qf1[qs], a, 0, 0, 0); \
        *(f32x4*)&Ss[h][qs*16 + ln][nt*16 + lg*4] = a; \
      } \
    } \
    __builtin_amdgcn_s_setprio(0); \
    LBAR();   /* Ss visible; orders prev PV Pb-reads vs softmax writes */ \
    _Pragma("unroll") \
    for (int i = 0; i < 2; i++){ \
      const int sq = sq0 + i*16; \
      float e0 = __builtin_amdgcn_exp2f(Ss[0][sq][sk]); \
      float e1 = __builtin_amdgcn_exp2f(Ss[1][sq][sk]); \
      float e2 = __builtin_amdgcn_exp2f(Ss[2][sq][sk]); \
      float e3 = __builtin_amdgcn_exp2f(Ss[3][sq][sk]); \
      float e4 = __builtin_amdgcn_exp2f(Ss[4][sq][sk]); \
      float e5 = __builtin_amdgcn_exp2f(Ss[5][sq][sk]); \
      float e6 = __builtin_amdgcn_exp2f(Ss[6][sq][sk]); \
      float e7 = __builtin_amdgcn_exp2f(Ss[7][sq][sk]); \
      float rs = __builtin_amdgcn_rcpf(((e0+e1)+(e2+e3))+((e4+e5)+(e6+e7))); \
      Pb[0][sq][sk] = f2bf_trunc(e0*rs); Pb[1][sq][sk] = f2bf_trunc(e1*rs); \
      Pb[2][sq][sk] = f2bf_trunc(e2*rs); Pb[3][sq][sk] = f2bf_trunc(e3*rs); \
      Pb[4][sq][sk] = f2bf_trunc(e4*rs); Pb[5][sq][sk] = f2bf_trunc(e5*rs); \
      Pb[6][sq][sk] = f2bf_trunc(e6*rs); Pb[7][sq][sk] = f2bf_trunc(e7*rs); \
    } \
    LBAR();   /* Pb visible; orders softmax Ss-reads vs next-iter writes */ \
    __builtin_amdgcn_s_setprio(1); \
    _Pragma("unroll") \
    for (int qs = 0; qs < 2; qs++){ \
      s16x8 pf = *(const s16x8*)&Pb[h][qs*16 + ln][lg*8]; \
      oacc[qs][0] = __builtin_amdgcn_mfma_f32_16x16x32_bf16(pf, vf0, oacc[qs][0], 0, 0, 0); \
      oacc[qs][1] = __builtin_amdgcn_mfma_f32_16x16x32_bf16(pf, vf1, oacc[qs][1], 0, 0, 0); \
      oacc[qs][2] = __builtin_amdgcn_mfma_f32_16x16x32_bf16(pf, vf2, oacc[qs][2], 0, 0, 0); \
    } \
    __builtin_amdgcn_s_setprio(0); \
    k0 = knx; \
  }

  for (int kt2 = 0; kt2 < SS/KT/2; kt2++){
    STEP(0, 1)
    STEP(1, 0)
  }
#undef STEP

  // store vals[b][h][q][d] fp32 (bug-compatible flat layout)
  float* op = vals + (hbase + q0)*HD;
  #pragma unroll
  for (int qs = 0; qs < 2; qs++)
    #pragma unroll
    for (int c = 0; c < 3; c++)
      #pragma unroll
      for (int r = 0; r < 4; r++)
        op[(long)(qs*16 + lg*4 + r)*HD + c*16 + ln] = oacc[qs][c][r];
}

// ---------------- Kernel 3: output projection, split-bf16 MFMA GEMM ----------------
__global__ __launch_bounds__(512, 4) void out_gemm(
    const float* __restrict__ A, const float* __restrict__ W,
    const float* __restrict__ bias, float* __restrict__ out)
{
  __shared__ u16 Ah[128][40], Al[128][40], Bh[128][40], Bl[128][40];
  const int tid  = threadIdx.x;
  const int w    = tid >> 6, lane = tid & 63;
  const int lg   = lane >> 4, ln = lane & 15;
  const int wm   = w >> 1, wn = w & 1;
  const int mb   = blockIdx.x / 3, nb = blockIdx.x % 3;
  const int m0   = mb * 128, n0 = nb * 128;
  const int srow = tid >> 3, sk4 = (tid & 7) << 2;

  f32x4 acc[8];
  #pragma unroll
  for (int i = 0; i < 8; i++) acc[i] = (f32x4){0.f,0.f,0.f,0.f};

  for (int ks = 0; ks < 12; ks++){
    const int k0 = ks * 32;
    __syncthreads();
    #pragma unroll
    for (int p = 0; p < 2; p++){
      const int row = srow + p*64;
      float4 av = *(const float4*)(A + (long)(m0+row)*DD + k0 + sk4);
      float4 bv = *(const float4*)(W + (long)(n0+row)*DD + k0 + sk4);
      u16 h0,l0,h1,l1,h2,l2,h3,l3;
      split2(av.x,h0,l0); split2(av.y,h1,l1); split2(av.z,h2,l2); split2(av.w,h3,l3);
      *(u16x4*)&Ah[row][sk4] = (u16x4){h0,h1,h2,h3};
      *(u16x4*)&Al[row][sk4] = (u16x4){l0,l1,l2,l3};
      split2(bv.x,h0,l0); split2(bv.y,h1,l1); split2(bv.z,h2,l2); split2(bv.w,h3,l3);
      *(u16x4*)&Bh[row][sk4] = (u16x4){h0,h1,h2,h3};
      *(u16x4*)&Bl[row][sk4] = (u16x4){l0,l1,l2,l3};
    }
    __syncthreads();
    s16x8 bh[4], bl[4];
    #pragma unroll
    for (int fn = 0; fn < 4; fn++){
      const int br = wn*64 + fn*16 + ln;
      bh[fn] = *(const s16x8*)&Bh[br][lg*8];
      bl[fn] = *(const s16x8*)&Bl[br][lg*8];
    }
    #pragma unroll
    for (int fm = 0; fm < 2; fm++){
      const int ar = wm*32 + fm*16 + ln;
      s16x8 ah = *(const s16x8*)&Ah[ar][lg*8];
      s16x8 al = *(const s16x8*)&Al[ar][lg*8];
      #pragma unroll
      for (int fn = 0; fn < 4; fn++){
        f32x4 c = acc[fm*4+fn];
        c = __builtin_amdgcn_mfma_f32_16x16x32_bf16(ah, bh[fn], c, 0, 0, 0);
        c = __builtin_amdgcn_mfma_f32_16x16x32_bf16(ah, bl[fn], c, 0, 0, 0);
        c = __builtin_amdgcn_mfma_f32_16x16x32_bf16(al, bh[fn], c, 0, 0, 0);
        acc[fm*4+fn] = c;
      }
    }
  }
  #pragma unroll
  for (int fm = 0; fm < 2; fm++){
    #pragma unroll
    for (int fn = 0; fn < 4; fn++){
      const int e = n0 + wn*64 + fn*16 + ln;
      const float bi = bias[e];
      #pragma unroll
      for (int r = 0; r < 4; r++){
        const int mm = m0 + wm*32 + fm*16 + lg*4 + r;
        out[(long)mm*DD + e] = acc[fm*4+fn][r] + bi;
      }
    }
  }
}

extern "C" void kernel_launch(void* const* d_in, const int* in_sizes, int n_in,
                              void* d_out, int out_size, void* d_ws, size_t ws_size,
                              hipStream_t stream)
{
  const float* x    = (const float*)d_in[0];
  const float* Wqkv = (const float*)d_in[1];
  const float* bqkv = (const float*)d_in[2];
  const float* Wo   = (const float*)d_in[3];
  const float* bo   = (const float*)d_in[4];
  float* out = (float*)d_out;

  const size_t QSZ = (size_t)BB*HH*SS*HD;   // 6,291,456 elems
  u16* Q  = (u16*)d_ws;
  u16* K  = Q + QSZ;
  u16* Vt = K + QSZ;                        // V^T [B,H,48,S]
  float* vals = (float*)(Vt + QSZ);         // fp32, 25.2 MB

  qkv_gemm<<<1152, 512, 0, stream>>>(x, Wqkv, bqkv, Q, K, Vt);
  attn_kernel<<<512, 512, 0, stream>>>(Q, K, Vt, vals);
  out_gemm<<<384, 512, 0, stream>>>(vals, Wo, bo, out);
}